// Round 11
// baseline (117.126 us; speedup 1.0000x reference)
//
#include <hip/hip_runtime.h>

#define B_SZ 256
#define C_SZ 1152
#define MO   128            // M*O = 8*16
#define CAPS_EPS 1e-8f

// Uniform tiling: 32 c-splits x 32 b-tiles, grid 1024, block 256 = 4 waves.
#define CSPL 32
#define CRNG (C_SZ / CSPL)  // 36 c per block
#define BPB  8              // b per block
#define CPW  (CRNG / 4)     // 9 c per wave

// ---------------------------------------------------------------------------
// Engine (rounds 6/10, proven): tile = 36c x 8b. Lane l holds W[c] rows
// mo=2l,2l+1 in 16 VGPRs (coalesced float4 loads, L2-hit across bt-blocks);
// u[8b][36c][8] staged once in LDS, hot loop reads broadcast ds_read_b128.
// NO u_hat materialization: h0,h1 are consumed in-register (rounds 2-10
// spent ~40us/pass writing+rereading a 75.5MB fp16 u_hat; four different
// store structures all stuck at ~2.4 TB/s effective).
//
// Softmax is fully in-wave: rows 2l,2l+1 share m = l>>3, so
//   logit partial = h0*v[2l] + h1*v[2l+1]          (one ds_read_b64)
//   o-reduce: xor 1,2,4 (8 lanes of same m)
//   softmax over m: xor 8,16,32 (8 m-groups, one e per distinct m)
// Per-lane acc[8b][2] -> cross-wave LDS reduce -> part[csp][b][128].

// P0: uniform weights 1/8 (softmax of zero logits) -> part0.
__global__ __launch_bounds__(256) void caps_pass0(
    const float* __restrict__ u,      // [B,C,8]
    const float* __restrict__ W,      // [C,128,8]
    float* __restrict__ part0)        // [CSPL,B,128]
{
    const int bid = blockIdx.x;
    const int csp = bid >> 5, bt = bid & 31;
    const int c0 = csp * CRNG, b0 = bt * BPB;
    const int tid = threadIdx.x, l = tid & 63, wv = tid >> 6;

    __shared__ __align__(16) float u_sh[BPB][292];      // 9.3 KB
    __shared__ __align__(16) float s_lds[4][BPB][MO];   // 16 KB

    for (int idx = tid; idx < BPB * 72; idx += 256) {
        const int bb = idx / 72, off = idx % 72;
        *reinterpret_cast<float4*>(&u_sh[bb][off * 4]) =
            *reinterpret_cast<const float4*>(
                u + ((size_t)(b0 + bb) * C_SZ + c0) * 8 + off * 4);
    }
    __syncthreads();

    float acc[BPB][2];
#pragma unroll
    for (int bb = 0; bb < BPB; ++bb) { acc[bb][0] = 0.f; acc[bb][1] = 0.f; }

    for (int k = 0; k < CPW; ++k) {
        const int cl = wv * CPW + k;
        const float4* wp = reinterpret_cast<const float4*>(
            W + (size_t)(c0 + cl) * 1024) + l * 4;
        const float4 wa = wp[0], wb = wp[1], wc4 = wp[2], wd = wp[3];
        const int cb = cl * 8;
#pragma unroll
        for (int bb = 0; bb < BPB; ++bb) {
            const float4 u0 = *reinterpret_cast<const float4*>(&u_sh[bb][cb]);
            const float4 u1 =
                *reinterpret_cast<const float4*>(&u_sh[bb][cb + 4]);
            acc[bb][0] += wa.x*u0.x + wa.y*u0.y + wa.z*u0.z + wa.w*u0.w
                        + wb.x*u1.x + wb.y*u1.y + wb.z*u1.z + wb.w*u1.w;
            acc[bb][1] += wc4.x*u0.x + wc4.y*u0.y + wc4.z*u0.z + wc4.w*u0.w
                        + wd.x*u1.x + wd.y*u1.y + wd.z*u1.z + wd.w*u1.w;
        }
    }

#pragma unroll
    for (int bb = 0; bb < BPB; ++bb)
        *reinterpret_cast<float2*>(&s_lds[wv][bb][2 * l]) =
            make_float2(acc[bb][0] * 0.125f, acc[bb][1] * 0.125f);
    __syncthreads();

    {   // 256 threads = 8 b x 32 float4: full [8][128]
        const int bb = tid >> 5, j = tid & 31;
        float4 r = make_float4(0.f, 0.f, 0.f, 0.f);
#pragma unroll
        for (int w = 0; w < 4; ++w) {
            const float4 x =
                *reinterpret_cast<const float4*>(&s_lds[w][bb][4 * j]);
            r.x += x.x; r.y += x.y; r.z += x.z; r.w += x.w;
        }
        *reinterpret_cast<float4*>(
            part0 + ((size_t)csp * B_SZ + b0 + bb) * MO + 4 * j) = r;
    }
}

// ---------------------------------------------------------------------------
// P1/P2: routing pass with fused v prologue (proven round-10 pattern) and
// on-the-fly u_hat recompute + in-wave softmax.
// PASS 1: v = squash(sum part_in) = v0; csp==0 persists v0.
// PASS 2: v = squash(sum part_in) + v0 (= vsum; b-linearity).
template <int PASS>
__global__ __launch_bounds__(256) void caps_pass12(
    const float* __restrict__ part_in,  // [CSPL,B,128]
    float* __restrict__ v0_io,          // [B,128] (out if PASS1, in if PASS2)
    const float* __restrict__ u,        // [B,C,8]
    const float* __restrict__ W,        // [C,128,8]
    float* __restrict__ part_out)       // [CSPL,B,128]
{
    const int bid = blockIdx.x;
    const int csp = bid >> 5, bt = bid & 31;
    const int c0 = csp * CRNG, b0 = bt * BPB;
    const int tid = threadIdx.x, l = tid & 63, wv = tid >> 6;

    __shared__ __align__(16) float u_sh[BPB][292];      // 9.3 KB
    __shared__ __align__(16) float v_sh[BPB][MO];       // 4 KB
    __shared__ __align__(16) float s_lds[4][BPB][MO];   // 16 KB

    for (int idx = tid; idx < BPB * 72; idx += 256) {
        const int bb = idx / 72, off = idx % 72;
        *reinterpret_cast<float4*>(&u_sh[bb][off * 4]) =
            *reinterpret_cast<const float4*>(
                u + ((size_t)(b0 + bb) * C_SZ + c0) * 8 + off * 4);
    }

    {   // v prologue: thread (bb = tid>>5, j = tid&31) owns mo 4j..4j+3
        const int bb = tid >> 5, j = tid & 31;
        float4 s = make_float4(0.f, 0.f, 0.f, 0.f);
        for (int k = 0; k < CSPL; ++k) {
            const float4 x = *reinterpret_cast<const float4*>(
                part_in + ((size_t)k * B_SZ + b0 + bb) * MO + 4 * j);
            s.x += x.x; s.y += x.y; s.z += x.z; s.w += x.w;
        }
        float n2 = s.x*s.x + s.y*s.y + s.z*s.z + s.w*s.w;
        n2 += __shfl_xor(n2, 1);
        n2 += __shfl_xor(n2, 2);       // 4 threads = 16 o of one (b,m)
        const float norm = sqrtf(n2);
        const float sc = (n2 / (1.f + n2)) / (norm + CAPS_EPS);
        float4 v = make_float4(s.x * sc, s.y * sc, s.z * sc, s.w * sc);
        if (PASS == 1) {
            if (csp == 0)
                *reinterpret_cast<float4*>(
                    v0_io + (size_t)(b0 + bb) * MO + 4 * j) = v;
        } else {
            const float4 p = *reinterpret_cast<const float4*>(
                v0_io + (size_t)(b0 + bb) * MO + 4 * j);
            v.x += p.x; v.y += p.y; v.z += p.z; v.w += p.w;
        }
        *reinterpret_cast<float4*>(&v_sh[bb][4 * j]) = v;
    }
    __syncthreads();

    float acc[BPB][2];
#pragma unroll
    for (int bb = 0; bb < BPB; ++bb) { acc[bb][0] = 0.f; acc[bb][1] = 0.f; }

    for (int k = 0; k < CPW; ++k) {
        const int cl = wv * CPW + k;
        const float4* wp = reinterpret_cast<const float4*>(
            W + (size_t)(c0 + cl) * 1024) + l * 4;
        const float4 wa = wp[0], wb = wp[1], wc4 = wp[2], wd = wp[3];
        const int cb = cl * 8;
#pragma unroll
        for (int bb = 0; bb < BPB; ++bb) {
            const float4 u0 = *reinterpret_cast<const float4*>(&u_sh[bb][cb]);
            const float4 u1 =
                *reinterpret_cast<const float4*>(&u_sh[bb][cb + 4]);
            const float h0 =
                  wa.x*u0.x + wa.y*u0.y + wa.z*u0.z + wa.w*u0.w
                + wb.x*u1.x + wb.y*u1.y + wb.z*u1.z + wb.w*u1.w;
            const float h1 =
                  wc4.x*u0.x + wc4.y*u0.y + wc4.z*u0.z + wc4.w*u0.w
                + wd.x*u1.x + wd.y*u1.y + wd.z*u1.z + wd.w*u1.w;

            const float2 vv =
                *reinterpret_cast<const float2*>(&v_sh[bb][2 * l]);
            float uv = h0 * vv.x + h1 * vv.y;
            uv += __shfl_xor(uv, 1);    // o-reduce within the 8-lane m-group
            uv += __shfl_xor(uv, 2);
            uv += __shfl_xor(uv, 4);
            float mx = fmaxf(uv, __shfl_xor(uv, 8));   // over 8 m-groups
            mx = fmaxf(mx, __shfl_xor(mx, 16));
            mx = fmaxf(mx, __shfl_xor(mx, 32));
            const float e = expf(uv - mx);
            float den = e + __shfl_xor(e, 8);
            den += __shfl_xor(den, 16);
            den += __shfl_xor(den, 32);
            const float cw = e / den;
            acc[bb][0] = fmaf(cw, h0, acc[bb][0]);
            acc[bb][1] = fmaf(cw, h1, acc[bb][1]);
        }
    }

#pragma unroll
    for (int bb = 0; bb < BPB; ++bb)
        *reinterpret_cast<float2*>(&s_lds[wv][bb][2 * l]) =
            make_float2(acc[bb][0], acc[bb][1]);
    __syncthreads();

    {
        const int bb = tid >> 5, j = tid & 31;
        float4 r = make_float4(0.f, 0.f, 0.f, 0.f);
#pragma unroll
        for (int w = 0; w < 4; ++w) {
            const float4 x =
                *reinterpret_cast<const float4*>(&s_lds[w][bb][4 * j]);
            r.x += x.x; r.y += x.y; r.z += x.z; r.w += x.w;
        }
        *reinterpret_cast<float4*>(
            part_out + ((size_t)csp * B_SZ + b0 + bb) * MO + 4 * j) = r;
    }
}

// ---------------------------------------------------------------------------
// K4: vout = squash(sum_{k<nsplit} part_in[k]). grid = B, block = 128.
__global__ __launch_bounds__(128) void caps_vcalc(
    const float* __restrict__ part_in,  // [nsplit,B,128]
    float* __restrict__ vout,           // [B,128]
    int nsplit)
{
    const int b = blockIdx.x, t = threadIdx.x;
    float s = 0.f;
    for (int k = 0; k < nsplit; ++k)
        s += part_in[((size_t)k * B_SZ + b) * MO + t];
    float n2 = s * s;                   // 16-lane group = one m row
    n2 += __shfl_xor(n2, 1);
    n2 += __shfl_xor(n2, 2);
    n2 += __shfl_xor(n2, 4);
    n2 += __shfl_xor(n2, 8);
    const float norm = sqrtf(n2);
    vout[(size_t)b * MO + t] = (n2 / (1.f + n2)) * s / (norm + CAPS_EPS);
}

// ---------------------------------------------------------------------------
// Fallback (small-ws): round-1 fused kernel, needs only 384 KB of ws.
template <int R>
__global__ __launch_bounds__(256) void caps_small(
    const float* __restrict__ u, const float* __restrict__ W,
    const float* __restrict__ s_in, const float* __restrict__ v0_in,
    float* __restrict__ s_out, float* __restrict__ v0_out,
    float* __restrict__ out)
{
    const int b = blockIdx.x, tid = threadIdx.x;
    __shared__ float sh_v[8][17];
    __shared__ float sh_part[256][17];

    if (R >= 1) {
        if (tid < 128) {
            float val = s_in[b * 128 + tid];
            float n2 = val * val;
            n2 += __shfl_xor(n2, 1); n2 += __shfl_xor(n2, 2);
            n2 += __shfl_xor(n2, 4); n2 += __shfl_xor(n2, 8);
            float norm = sqrtf(n2);
            float v = (n2 / (1.f + n2)) * val / (norm + CAPS_EPS);
            int m = tid >> 4, o = tid & 15;
            if (R == 1) { v0_out[b * 128 + tid] = v; sh_v[m][o] = v; }
            else        { sh_v[m][o] = v + v0_in[b * 128 + tid]; }
        }
        __syncthreads();
    }
    const int c_local = tid >> 3, m = tid & 7;
    float s_acc[16];
#pragma unroll
    for (int o = 0; o < 16; ++o) s_acc[o] = 0.f;
    for (int cc = 0; cc < C_SZ; cc += 32) {
        const int c = cc + c_local;
        const float4* up = reinterpret_cast<const float4*>(
            u + (size_t)(b * C_SZ + c) * 8);
        float4 u0 = up[0], u1 = up[1];
        float u8[8] = {u0.x, u0.y, u0.z, u0.w, u1.x, u1.y, u1.z, u1.w};
        float uh[16];
        const float4* wp = reinterpret_cast<const float4*>(
            W + (size_t)((c * 8 + m) * 16) * 8);
#pragma unroll
        for (int o = 0; o < 16; ++o) {
            float4 w0 = wp[o * 2], w1 = wp[o * 2 + 1];
            uh[o] = w0.x * u8[0] + w0.y * u8[1] + w0.z * u8[2] + w0.w * u8[3] +
                    w1.x * u8[4] + w1.y * u8[5] + w1.z * u8[6] + w1.w * u8[7];
        }
        float cw;
        if (R == 0) cw = 0.125f;
        else {
            float uv = 0.f;
#pragma unroll
            for (int o = 0; o < 16; ++o) uv = fmaf(uh[o], sh_v[m][o], uv);
            float mx = uv;
            mx = fmaxf(mx, __shfl_xor(mx, 1));
            mx = fmaxf(mx, __shfl_xor(mx, 2));
            mx = fmaxf(mx, __shfl_xor(mx, 4));
            float e = expf(uv - mx);
            float den = e;
            den += __shfl_xor(den, 1); den += __shfl_xor(den, 2);
            den += __shfl_xor(den, 4);
            cw = e / den;
        }
#pragma unroll
        for (int o = 0; o < 16; ++o) s_acc[o] = fmaf(cw, uh[o], s_acc[o]);
    }
#pragma unroll
    for (int o = 0; o < 16; ++o) sh_part[tid][o] = s_acc[o];
    __syncthreads();
    if (tid < 128) {
        const int m2 = tid >> 4, o2 = tid & 15;
        float s = 0.f;
#pragma unroll
        for (int gg = 0; gg < 32; ++gg) s += sh_part[gg * 8 + m2][o2];
        if (R < 2) s_out[b * 128 + tid] = s;
        else {
            float n2 = s * s;
            n2 += __shfl_xor(n2, 1); n2 += __shfl_xor(n2, 2);
            n2 += __shfl_xor(n2, 4); n2 += __shfl_xor(n2, 8);
            float norm = sqrtf(n2);
            out[b * 128 + tid] = (n2 / (1.f + n2)) * s / (norm + CAPS_EPS);
        }
    }
}

extern "C" void kernel_launch(void* const* d_in, const int* in_sizes, int n_in,
                              void* d_out, int out_size, void* d_ws, size_t ws_size,
                              hipStream_t stream) {
    const float* u = (const float*)d_in[0];  // [256,1152,8]
    const float* W = (const float*)d_in[1];  // [1152,8,16,8]
    float* out = (float*)d_out;              // [256,8,16]

    const size_t PR_FLOATS = (size_t)CSPL * B_SZ * MO;   // 4.2 MB
    const size_t NEED = (2 * PR_FLOATS + B_SZ * MO) * 4; // ~8.5 MB

    if (ws_size >= NEED) {
        float* part0 = (float*)d_ws;          // P0 out / P2 out (reused)
        float* partA = part0 + PR_FLOATS;     // P1 out
        float* v0    = partA + PR_FLOATS;

        dim3 blk(256), grid(CSPL * 32);
        caps_pass0    <<<grid, blk, 0, stream>>>(u, W, part0);
        caps_pass12<1><<<grid, blk, 0, stream>>>(part0, v0, u, W, partA);
        caps_pass12<2><<<grid, blk, 0, stream>>>(partA, v0, u, W, part0);
        caps_vcalc<<<dim3(B_SZ), dim3(128), 0, stream>>>(part0, out, CSPL);
    } else {
        // small-ws fallback (round-1 path)
        float* sA = (float*)d_ws;
        float* sB = sA + 32768;
        float* v0 = sB + 32768;
        dim3 grid(B_SZ), blk(256);
        caps_small<0><<<grid, blk, 0, stream>>>(u, W, nullptr, nullptr, sA, nullptr, nullptr);
        caps_small<1><<<grid, blk, 0, stream>>>(u, W, sA, nullptr, sB, v0, nullptr);
        caps_small<2><<<grid, blk, 0, stream>>>(u, W, sB, v0, nullptr, nullptr, out);
    }
}